// Round 2
// baseline (414.693 us; speedup 1.0000x reference)
//
#include <hip/hip_runtime.h>

typedef _Float16 half8 __attribute__((ext_vector_type(8)));
typedef float floatx4 __attribute__((ext_vector_type(4)));

constexpr int IN_F  = 8192;
constexpr int OUT_F = 8192;
constexpr int NCOL  = 16;

constexpr int WVS   = 8;                 // waves per block (512 threads)
constexpr int ROWS  = 32;                // output rows per block
constexpr int RB    = ROWS / 16;         // 2 row-tiles per wave (bf reuse x2)
constexpr int KCHUNK = IN_F / WVS;       // 1024 k per wave
constexpr int WIN    = 128;              // k per bf-register window
constexpr int NWIN   = KCHUNK / WIN;     // 8
constexpr int STEPS  = WIN / 32;         // 4 MFMA k-steps per window
constexpr int NBLOCKS = OUT_F / ROWS;    // 256 = one block per CU

// D = W @ x. W as MFMA A-operand (16 rows), x as B (16 cols), fp32 acc.
// Layouts (gfx950, HW-verified in prior session): A[m=lane&15][k=quad*8+j],
// B[k=quad*8+j][n=lane&15], C/D: col=lane&15, row=quad*4+reg.
//
// Structure: block = 32 rows x full K. 8 waves split K (1024 each); each
// wave computes BOTH 16-row tiles with the same register-resident B
// fragments (halves the stride-64B x-load overhead vs 1 tile/wave).
// Partials meet in a 16 KB LDS reduction -> one coalesced 2 KB store.
// No atomics, no output pre-zeroing, deterministic.
__global__ __launch_bounds__(512, 2)
void lq_mfma_kernel(const float* __restrict__ x,
                    const void* __restrict__ wraw,
                    const float* __restrict__ scaler,
                    float* __restrict__ out)
{
    __shared__ float red[WVS * ROWS * NCOL];     // 8 x 32 x 16 fp32 = 16 KB

    const int tid  = threadIdx.x;
    const int lane = tid & 63;
    const int wv   = tid >> 6;
    const int m    = lane & 15;          // A row-in-tile == C col
    const int quad = lane >> 4;
    const int row0 = blockIdx.x * ROWS;
    const int k0   = wv * KCHUNK;

    // ---- dtype probe: int32-materialized weights vs raw int8 (wave-uniform,
    // one cache line, verified in prior session) ----
    const int* wi = (const int*)wraw;
    bool w_is_i32 = true;
    #pragma unroll
    for (int i = 0; i < 16; ++i) {
        int v = wi[i];
        w_is_i32 = w_is_i32 && (v >= -128) && (v <= 127);
    }

    const float* xp = x + (size_t)(k0 + quad * 8) * NCOL + m;

    floatx4 acc0 = {0.f, 0.f, 0.f, 0.f};
    floatx4 acc1 = {0.f, 0.f, 0.f, 0.f};

    if (w_is_i32) {
        // ---- path A: weights materialized as int32 (268 MB stream) ----
        const int* wbase = (const int*)wraw + (size_t)(row0 + m) * IN_F + k0 + quad * 8;
        #pragma unroll 2
        for (int w = 0; w < NWIN; ++w) {
            const int kb = w * WIN;
            half8 bf[STEPS];
            #pragma unroll
            for (int st = 0; st < STEPS; ++st) {
                #pragma unroll
                for (int j = 0; j < 8; ++j)
                    bf[st][j] = (_Float16)xp[(kb + st * 32 + j) * NCOL];
            }
            #pragma unroll
            for (int st = 0; st < STEPS; ++st) {
                half8 af0, af1;
                #pragma unroll
                for (int j = 0; j < 8; ++j) {
                    af0[j] = (_Float16)wbase[kb + st * 32 + j];
                    af1[j] = (_Float16)wbase[(size_t)16 * IN_F + kb + st * 32 + j];
                }
                acc0 = __builtin_amdgcn_mfma_f32_16x16x32_f16(af0, bf[st], acc0, 0, 0, 0);
                acc1 = __builtin_amdgcn_mfma_f32_16x16x32_f16(af1, bf[st], acc1, 0, 0, 0);
            }
        }
    } else {
        // ---- path B: weights raw int8 (64 MB stream) ----
        const signed char* wbase = (const signed char*)wraw + (size_t)(row0 + m) * IN_F + k0 + quad * 8;
        #pragma unroll 2
        for (int w = 0; w < NWIN; ++w) {
            const int kb = w * WIN;
            half8 bf[STEPS];
            #pragma unroll
            for (int st = 0; st < STEPS; ++st) {
                #pragma unroll
                for (int j = 0; j < 8; ++j)
                    bf[st][j] = (_Float16)xp[(kb + st * 32 + j) * NCOL];
            }
            #pragma unroll
            for (int st = 0; st < STEPS; ++st) {
                const uint2 u0 = *(const uint2*)(wbase + kb + st * 32);
                const uint2 u1 = *(const uint2*)(wbase + (size_t)16 * IN_F + kb + st * 32);
                half8 af0, af1;
                #pragma unroll
                for (int j = 0; j < 4; ++j) {
                    af0[j]     = (_Float16)(int)(signed char)(u0.x >> (8 * j));
                    af0[j + 4] = (_Float16)(int)(signed char)(u0.y >> (8 * j));
                    af1[j]     = (_Float16)(int)(signed char)(u1.x >> (8 * j));
                    af1[j + 4] = (_Float16)(int)(signed char)(u1.y >> (8 * j));
                }
                acc0 = __builtin_amdgcn_mfma_f32_16x16x32_f16(af0, bf[st], acc0, 0, 0, 0);
                acc1 = __builtin_amdgcn_mfma_f32_16x16x32_f16(af1, bf[st], acc1, 0, 0, 0);
            }
        }
    }

    // ---- cross-wave reduction in LDS, single coalesced store ----
    #pragma unroll
    for (int g = 0; g < 4; ++g) {
        red[wv * (ROWS * NCOL) + (quad * 4 + g) * NCOL + m]            = acc0[g];
        red[wv * (ROWS * NCOL) + (16 + quad * 4 + g) * NCOL + m]       = acc1[g];
    }
    __syncthreads();

    // 512 threads -> 512 outputs (32 rows x 16 cols), fully coalesced.
    float sum = 0.f;
    #pragma unroll
    for (int v = 0; v < WVS; ++v)
        sum += red[v * (ROWS * NCOL) + tid];
    out[(size_t)row0 * NCOL + tid] = sum * scaler[0];
}

extern "C" void kernel_launch(void* const* d_in, const int* in_sizes, int n_in,
                              void* d_out, int out_size, void* d_ws, size_t ws_size,
                              hipStream_t stream)
{
    const float* x      = (const float*)d_in[0];
    const void*  w      = d_in[1];
    const float* scaler = (const float*)d_in[2];
    float*       out    = (float*)d_out;

    // No cross-block K-split -> no atomics -> no output pre-zeroing.
    lq_mfma_kernel<<<NBLOCKS, 512, 0, stream>>>(x, w, scaler, out);
}

// Round 4
// 389.587 us; speedup vs baseline: 1.0644x; 1.0644x over previous
//
#include <hip/hip_runtime.h>

typedef _Float16 half8 __attribute__((ext_vector_type(8)));
typedef float floatx4 __attribute__((ext_vector_type(4)));

constexpr int IN_F  = 8192;
constexpr int OUT_F = 8192;
constexpr int NCOL  = 16;

constexpr int WVS    = 8;                // waves per block (512 threads)
constexpr int KCHUNK = IN_F / WVS;       // 1024 k per wave
constexpr int WIN    = 128;              // k per pipelined window
constexpr int NWIN   = KCHUNK / WIN;     // 8
constexpr int STEPS  = WIN / 32;         // 4 MFMA k-steps per window
constexpr int NBLOCKS = OUT_F / 16;      // 512 blocks: one 16-row tile, full K

// ---------------------------------------------------------------------------
// Pre-pass: xt[n][k] (f16) = (f16)x[k][n].  512 KB -> 256 KB, one-shot.
// Makes B-fragment loads a single dwordx4 (vs 8 scalar stride-64B + 8 cvt).
// ---------------------------------------------------------------------------
__global__ __launch_bounds__(256)
void xt_kernel(const float* __restrict__ x, _Float16* __restrict__ xt)
{
    const int t  = blockIdx.x * 256 + threadIdx.x;   // 16384 threads
    const int n  = t >> 10;                          // 0..15
    const int kb = (t & 1023) * 8;                   // 0..8184
    half8 v;
    #pragma unroll
    for (int j = 0; j < 8; ++j)
        v[j] = (_Float16)x[(size_t)(kb + j) * NCOL + n];
    *(half8*)(xt + (size_t)n * IN_F + kb) = v;       // coalesced 16B stores
}

// ---------------------------------------------------------------------------
// D = W @ x. W as MFMA A-operand (16 rows), x as B (16 cols), fp32 acc.
// Layouts (gfx950, HW-verified): A[m=lane&15][k=quad*8+j],
// B[k=quad*8+j][n=lane&15], C/D: col=lane&15, row=quad*4+reg.
//
// Geometry (empirically best, round 1): 512 blocks x 512 thr (16 waves/CU),
// 8-wave intra-block K-split (1024 k each), LDS reduction, no atomics.
// Pipeline: fully-unrolled 8-window loop, register double-buffer — window
// w+1's loads (8x dwordx4 W + 4x dwordx4 x) issue before window w's
// compute, so one full window stays in flight (counted vmcnt). The current
// window's ints are converted to f16 right after the prefetch issues, so
// only one raw uint4 window is ever live (keeps VGPR under the (512,4) cap).
// ---------------------------------------------------------------------------
template<bool XT>
__global__ __launch_bounds__(512, 4)
void lq_mfma_kernel(const float* __restrict__ x,
                    const _Float16* __restrict__ xt,
                    const void* __restrict__ wraw,
                    const float* __restrict__ scaler,
                    float* __restrict__ out)
{
    __shared__ float red[WVS * 256];     // 8 waves x (16 rows x 16 cols)

    const int tid  = threadIdx.x;
    const int lane = tid & 63;
    const int wv   = tid >> 6;
    const int m    = lane & 15;          // A row-in-tile == C col
    const int quad = lane >> 4;
    const int row0 = blockIdx.x * 16;
    const int k0   = wv * KCHUNK;

    // ---- dtype probe: int32-materialized weights vs raw int8 (wave-uniform,
    // one cache line; harness-verified in prior rounds) ----
    const int* wi = (const int*)wraw;
    bool w_is_i32 = true;
    #pragma unroll
    for (int i = 0; i < 16; ++i) {
        int v = wi[i];
        w_is_i32 = w_is_i32 && (v >= -128) && (v <= 127);
    }

    floatx4 acc = {0.f, 0.f, 0.f, 0.f};

    // B-fragment window loader (4 x half8). XT: one dwordx4 per step.
    const _Float16* xtp = xt + (size_t)m * IN_F + k0 + quad * 8;
    const float*    xp  = x + (size_t)(k0 + quad * 8) * NCOL + m;
    auto load_bf = [&](int kb, half8* bf) {
        if constexpr (XT) {
            #pragma unroll
            for (int st = 0; st < STEPS; ++st)
                bf[st] = *(const half8*)(xtp + kb + st * 32);
        } else {
            #pragma unroll
            for (int st = 0; st < STEPS; ++st)
                #pragma unroll
                for (int j = 0; j < 8; ++j)
                    bf[st][j] = (_Float16)xp[(size_t)(kb + st * 32 + j) * NCOL];
        }
    };

    if (w_is_i32) {
        // ---- path A: weights materialized as int32 (268 MB stream) ----
        const uint4* wbase = (const uint4*)((const int*)wraw
                             + (size_t)(row0 + m) * IN_F + k0 + quad * 8);
        uint4 wa[2 * STEPS];             // raw ints of ONE in-flight window
        half8 af[STEPS];                 // converted A-fragments (current)
        half8 ba[2][STEPS];

        #pragma unroll
        for (int st = 0; st < STEPS; ++st) {
            wa[st * 2]     = wbase[st * 8];
            wa[st * 2 + 1] = wbase[st * 8 + 1];
        }
        load_bf(0, ba[0]);

        #pragma unroll
        for (int w = 0; w < NWIN; ++w) {
            const int cur = w & 1, nxt = cur ^ 1;
            // convert current window raw->f16 into af (frees wa for prefetch)
            half8 afc[STEPS];
            #pragma unroll
            for (int st = 0; st < STEPS; ++st) {
                const uint4 a = wa[st * 2], b = wa[st * 2 + 1];
                afc[st][0] = (_Float16)(int)a.x;  afc[st][1] = (_Float16)(int)a.y;
                afc[st][2] = (_Float16)(int)a.z;  afc[st][3] = (_Float16)(int)a.w;
                afc[st][4] = (_Float16)(int)b.x;  afc[st][5] = (_Float16)(int)b.y;
                afc[st][6] = (_Float16)(int)b.z;  afc[st][7] = (_Float16)(int)b.w;
            }
            if (w + 1 < NWIN) {                       // prefetch window w+1
                const uint4* wn = wbase + (size_t)(w + 1) * (WIN / 4);
                #pragma unroll
                for (int st = 0; st < STEPS; ++st) {
                    wa[st * 2]     = wn[st * 8];
                    wa[st * 2 + 1] = wn[st * 8 + 1];
                }
                load_bf((w + 1) * WIN, ba[nxt]);
            }
            #pragma unroll
            for (int st = 0; st < STEPS; ++st)        // compute window w
                acc = __builtin_amdgcn_mfma_f32_16x16x32_f16(afc[st], ba[cur][st], acc, 0, 0, 0);
        }
    } else {
        // ---- path B: weights raw int8 (64 MB stream) ----
        const signed char* wbase = (const signed char*)wraw
                                   + (size_t)(row0 + m) * IN_F + k0 + quad * 8;
        uint2 wa[STEPS];
        half8 ba[2][STEPS];

        #pragma unroll
        for (int st = 0; st < STEPS; ++st)
            wa[st] = *(const uint2*)(wbase + st * 32);
        load_bf(0, ba[0]);

        #pragma unroll
        for (int w = 0; w < NWIN; ++w) {
            const int cur = w & 1, nxt = cur ^ 1;
            half8 afc[STEPS];
            #pragma unroll
            for (int st = 0; st < STEPS; ++st) {
                const uint2 u = wa[st];
                #pragma unroll
                for (int j = 0; j < 4; ++j) {
                    afc[st][j]     = (_Float16)(int)(signed char)(u.x >> (8 * j));
                    afc[st][j + 4] = (_Float16)(int)(signed char)(u.y >> (8 * j));
                }
            }
            if (w + 1 < NWIN) {
                const signed char* wn = wbase + (size_t)(w + 1) * WIN;
                #pragma unroll
                for (int st = 0; st < STEPS; ++st)
                    wa[st] = *(const uint2*)(wn + st * 32);
                load_bf((w + 1) * WIN, ba[nxt]);
            }
            #pragma unroll
            for (int st = 0; st < STEPS; ++st)
                acc = __builtin_amdgcn_mfma_f32_16x16x32_f16(afc[st], ba[cur][st], acc, 0, 0, 0);
        }
    }

    // ---- cross-wave reduction in LDS, single coalesced store ----
    #pragma unroll
    for (int g = 0; g < 4; ++g)
        red[wv * 256 + (quad * 4 + g) * 16 + m] = acc[g];
    __syncthreads();

    if (tid < 256) {
        float sum = 0.f;
        #pragma unroll
        for (int v = 0; v < WVS; ++v)
            sum += red[v * 256 + tid];
        out[(size_t)row0 * NCOL + tid] = sum * scaler[0];
    }
}

extern "C" void kernel_launch(void* const* d_in, const int* in_sizes, int n_in,
                              void* d_out, int out_size, void* d_ws, size_t ws_size,
                              hipStream_t stream)
{
    const float* x      = (const float*)d_in[0];
    const void*  w      = d_in[1];
    const float* scaler = (const float*)d_in[2];
    float*       out    = (float*)d_out;

    const size_t xt_bytes = (size_t)IN_F * NCOL * sizeof(_Float16);  // 256 KB
    if (ws_size >= xt_bytes) {
        _Float16* xt = (_Float16*)d_ws;
        xt_kernel<<<(IN_F * NCOL / 8) / 256, 256, 0, stream>>>(x, xt);
        lq_mfma_kernel<true><<<NBLOCKS, 512, 0, stream>>>(x, xt, w, scaler, out);
    } else {
        lq_mfma_kernel<false><<<NBLOCKS, 512, 0, stream>>>(x, nullptr, w, scaler, out);
    }
}

// Round 5
// 366.023 us; speedup vs baseline: 1.1330x; 1.0644x over previous
//
#include <hip/hip_runtime.h>

typedef _Float16 half8 __attribute__((ext_vector_type(8)));
typedef float floatx4 __attribute__((ext_vector_type(4)));
typedef int int4v __attribute__((ext_vector_type(4)));

constexpr int IN_F  = 8192;
constexpr int OUT_F = 8192;
constexpr int NCOL  = 16;

constexpr int WVS     = 8;               // waves per block (512 threads)
constexpr int BK      = 256;             // k (ints) per LDS tile
constexpr int NT      = IN_F / BK;       // 32 tiles
constexpr int NBLOCKS = OUT_F / 16;      // 512 blocks: 16 rows, full K

// ---------------------------------------------------------------------------
// Pre-pass: xt[n][k] (f16) = (f16)x[k][n].  512 KB -> 256 KB, one-shot.
// ---------------------------------------------------------------------------
__global__ __launch_bounds__(256)
void xt_kernel(const float* __restrict__ x, _Float16* __restrict__ xt)
{
    const int t  = blockIdx.x * 256 + threadIdx.x;   // 16384 threads
    const int n  = t >> 10;                          // 0..15
    const int kb = (t & 1023) * 8;                   // 0..8184
    half8 v;
    #pragma unroll
    for (int j = 0; j < 8; ++j)
        v[j] = (_Float16)x[(size_t)(kb + j) * NCOL + n];
    *(half8*)(xt + (size_t)n * IN_F + kb) = v;       // coalesced 16B stores
}

// ---------------------------------------------------------------------------
// D = W @ x. W as MFMA A-operand (16 rows), x as B (16 cols), fp32 acc.
// Layouts (gfx950, HW-verified): A[m=lane&15][k=quad*8+j],
// B[k=quad*8+j][n=lane&15], C/D: col=lane&15, row=quad*4+reg.
//
// W is staged to LDS via global_load_lds width=16: each staging instruction
// reads 1 KB FULLY CONTIGUOUS from one W row (full cache lines, one
// sequential stream per row) instead of the register path's 16-rows x
// half-covered-lines pattern. LDS dest is linear; the *global source* is
// XOR-pre-swizzled per lane and the same XOR is applied on ds_read
// (rule: both-sides-or-neither), giving conflict-free ds_read_b128.
// x fragments are staged the same way (from f16-transposed xt in ws), so
// the main loop has no register-path VMEM and vmcnt counting is exact:
// 3 global_load_lds per wave per tile -> s_waitcnt vmcnt(3).
// Geometry: 512 blocks x 8 waves; wave wv computes k-slice [wv*32,wv*32+32)
// of each 256-k tile; partials meet in an LDS reduction. No atomics.
// ---------------------------------------------------------------------------
template<bool XT>
__global__ __launch_bounds__(512, 4)
void lq_mfma_kernel(const float* __restrict__ x,
                    const _Float16* __restrict__ xt,
                    const void* __restrict__ wraw,
                    const float* __restrict__ scaler,
                    float* __restrict__ out)
{
    // bytes [0,32768): W double buffer (2 x 16 rows x 1 KB)
    // bytes [32768,49152): xt double buffer (2 x 16 n-rows x 512 B)
    __shared__ int smem[12288];          // 48 KB

    const int tid  = threadIdx.x;
    const int lane = tid & 63;
    const int wv   = tid >> 6;
    const int m    = lane & 15;          // A row-in-tile == C col
    const int quad = lane >> 4;
    const int row0 = blockIdx.x * 16;

    // ---- dtype probe: int32-materialized weights vs raw int8 (wave-uniform,
    // one cache line; harness-verified in prior rounds) ----
    const int* wi = (const int*)wraw;
    bool w_is_i32 = true;
    #pragma unroll
    for (int i = 0; i < 16; ++i) {
        int v = wi[i];
        w_is_i32 = w_is_i32 && (v >= -128) && (v <= 127);
    }

    floatx4 acc = {0.f, 0.f, 0.f, 0.f};

    if (XT && w_is_i32) {
        // ---- staged path (live): weights int32, x from transposed f16 ----
        // Staging sources: wave wv stages W rows 2wv, 2wv+1 (1 KB each) and
        // xt rows 2wv (lanes 0-31) / 2wv+1 (lanes 32-63) (512 B each).
        const int r0s = wv * 2, r1s = wv * 2 + 1;
        const char* wsrc0 = (const char*)wraw + (size_t)(row0 + r0s) * (IN_F * 4)
                          + ((lane * 16) ^ ((r0s & 7) << 4));
        const char* wsrc1 = (const char*)wraw + (size_t)(row0 + r1s) * (IN_F * 4)
                          + ((lane * 16) ^ ((r1s & 7) << 4));
        const int   nst   = wv * 2 + (lane >> 5);
        const char* xsrc  = (const char*)xt + (size_t)nst * (IN_F * 2)
                          + (((lane & 31) * 16) ^ ((wv & 7) << 4));

        // Swizzled read offsets (bytes).  A: slot m, in-row byte
        // g = wv*128 + quad*32 (+16);  B: slot m>>1, half m&1, in-half byte
        // h = wv*64 + quad*16.  Same XOR as staging -> involution.
        const int aoff0 = m * 1024 + (((wv * 128) + quad * 32)      ^ ((m & 7) << 4));
        const int aoff1 = m * 1024 + (((wv * 128) + quad * 32 + 16) ^ ((m & 7) << 4));
        const int boff  = (m >> 1) * 1024 + (m & 1) * 512
                        + (((wv * 64) + quad * 16) ^ (((m >> 1) & 7) << 4));

        auto stage = [&](int t, int b) {
            int* wd0 = smem + b * 4096 + r0s * 256;
            int* wd1 = smem + b * 4096 + r1s * 256;
            int* xd  = smem + 8192 + b * 2048 + wv * 256;
            __builtin_amdgcn_global_load_lds(
                (const __attribute__((address_space(1))) unsigned*)(wsrc0 + (size_t)t * 1024),
                (__attribute__((address_space(3))) unsigned*)wd0, 16, 0, 0);
            __builtin_amdgcn_global_load_lds(
                (const __attribute__((address_space(1))) unsigned*)(wsrc1 + (size_t)t * 1024),
                (__attribute__((address_space(3))) unsigned*)wd1, 16, 0, 0);
            __builtin_amdgcn_global_load_lds(
                (const __attribute__((address_space(1))) unsigned*)(xsrc + (size_t)t * 512),
                (__attribute__((address_space(3))) unsigned*)xd, 16, 0, 0);
        };

        stage(0, 0);
        #pragma unroll 1
        for (int t = 0; t < NT; ++t) {
            const int b = t & 1;
            if (t + 1 < NT) {
                stage(t + 1, b ^ 1);                  // 3 new gll in flight
                asm volatile("s_waitcnt vmcnt(3)" ::: "memory");  // drain tile t's 3
            } else {
                asm volatile("s_waitcnt vmcnt(0)" ::: "memory");
            }
            __syncthreads();                          // all waves' tile t landed

            const char* wb = (const char*)smem + b * 16384;
            const char* xb = (const char*)smem + 32768 + b * 8192;
            const int4v a0 = *(const int4v*)(wb + aoff0);   // ds_read_b128
            const int4v a1 = *(const int4v*)(wb + aoff1);   // ds_read_b128
            const half8 bf = *(const half8*)(xb + boff);    // ds_read_b128
            half8 af;
            af[0] = (_Float16)a0[0];  af[1] = (_Float16)a0[1];
            af[2] = (_Float16)a0[2];  af[3] = (_Float16)a0[3];
            af[4] = (_Float16)a1[0];  af[5] = (_Float16)a1[1];
            af[6] = (_Float16)a1[2];  af[7] = (_Float16)a1[3];
            acc = __builtin_amdgcn_mfma_f32_16x16x32_f16(af, bf, acc, 0, 0, 0);

            __syncthreads();                          // protect buffer reuse
        }
    } else {
        // ---- fallback (never fires in this harness): round-1 register path ----
        const int k0 = wv * 1024;
        const float* xp = x + (size_t)(k0 + quad * 8) * NCOL + m;
        if (w_is_i32) {
            const int* wrow = (const int*)wraw + (size_t)(row0 + m) * IN_F + k0 + quad * 8;
            #pragma unroll 1
            for (int st = 0; st < 32; ++st) {
                half8 bfr, afr;
                #pragma unroll
                for (int j = 0; j < 8; ++j) {
                    bfr[j] = (_Float16)xp[(size_t)(st * 32 + j) * NCOL];
                    afr[j] = (_Float16)wrow[st * 32 + j];
                }
                acc = __builtin_amdgcn_mfma_f32_16x16x32_f16(afr, bfr, acc, 0, 0, 0);
            }
        } else {
            const signed char* wrow = (const signed char*)wraw + (size_t)(row0 + m) * IN_F + k0 + quad * 8;
            #pragma unroll 1
            for (int st = 0; st < 32; ++st) {
                half8 bfr, afr;
                #pragma unroll
                for (int j = 0; j < 8; ++j)
                    bfr[j] = (_Float16)xp[(size_t)(st * 32 + j) * NCOL];
                const uint2 u = *(const uint2*)(wrow + st * 32);
                #pragma unroll
                for (int j = 0; j < 4; ++j) {
                    afr[j]     = (_Float16)(int)(signed char)(u.x >> (8 * j));
                    afr[j + 4] = (_Float16)(int)(signed char)(u.y >> (8 * j));
                }
                acc = __builtin_amdgcn_mfma_f32_16x16x32_f16(afr, bfr, acc, 0, 0, 0);
            }
        }
        __syncthreads();   // align with staged path before smem reuse
    }

    // ---- cross-wave reduction in LDS (aliases staging buffers; all staging
    // drained and all waves synced above), single coalesced store ----
    float* red = (float*)smem;
    #pragma unroll
    for (int g = 0; g < 4; ++g)
        red[wv * 256 + (quad * 4 + g) * 16 + m] = acc[g];
    __syncthreads();

    if (tid < 256) {
        float sum = 0.f;
        #pragma unroll
        for (int v = 0; v < WVS; ++v)
            sum += red[v * 256 + tid];
        out[(size_t)row0 * NCOL + tid] = sum * scaler[0];
    }
}

extern "C" void kernel_launch(void* const* d_in, const int* in_sizes, int n_in,
                              void* d_out, int out_size, void* d_ws, size_t ws_size,
                              hipStream_t stream)
{
    const float* x      = (const float*)d_in[0];
    const void*  w      = d_in[1];
    const float* scaler = (const float*)d_in[2];
    float*       out    = (float*)d_out;

    const size_t xt_bytes = (size_t)IN_F * NCOL * sizeof(_Float16);  // 256 KB
    if (ws_size >= xt_bytes) {
        _Float16* xtp = (_Float16*)d_ws;
        xt_kernel<<<(IN_F * NCOL / 8) / 256, 256, 0, stream>>>(x, xtp);
        lq_mfma_kernel<true><<<NBLOCKS, 512, 0, stream>>>(x, xtp, w, scaler, out);
    } else {
        lq_mfma_kernel<false><<<NBLOCKS, 512, 0, stream>>>(x, nullptr, w, scaler, out);
    }
}